// Round 1
// baseline (504.459 us; speedup 1.0000x reference)
//
#include <hip/hip_runtime.h>
#include <math.h>

constexpr int kM0 = 16, kM1 = 8, kDim = 40, kNW = 576;
constexpr int kNodes = 10000, kEdges = 160000;

__device__ __forceinline__ float sspf(float x){
  // softplus(x) - ln2  (numerically stable)
  float ax = fabsf(x);
  return fmaxf(x, 0.f) + log1pf(expf(-ax)) - 0.69314718055994531f;
}

// ---------------- h = _lin(x, W1s, W1v) ----------------
__global__ void __launch_bounds__(256) k_prep(
    const float* __restrict__ x, const float* __restrict__ W1s,
    const float* __restrict__ W1v, float* __restrict__ h){
  int n = blockIdx.x*256 + threadIdx.x;
  if (n >= kNodes) return;
  const float* xp = x + n*kDim;
  float* hp = h + n*kDim;
  #pragma unroll
  for (int v=0; v<kM0; ++v){
    float acc = 0.f;
    #pragma unroll
    for (int u=0; u<kM0; ++u) acc += xp[u]*W1s[u*kM0+v];
    hp[v] = acc*0.25f;                       // 1/sqrt(16)
  }
  #pragma unroll
  for (int v=0; v<kM1; ++v){
    float a0=0.f,a1=0.f,a2=0.f;
    #pragma unroll
    for (int u=0; u<kM1; ++u){
      float wv = W1v[u*kM1+v];
      a0 += xp[16+u*3+0]*wv;
      a1 += xp[16+u*3+1]*wv;
      a2 += xp[16+u*3+2]*wv;
    }
    hp[16+v*3+0]=a0*0.35355339059327373f;    // 1/sqrt(8)
    hp[16+v*3+1]=a1*0.35355339059327373f;
    hp[16+v*3+2]=a2*0.35355339059327373f;
  }
}

// ---------------- per-edge messages + scatter ----------------
__global__ void __launch_bounds__(256) k_edge(
    const float* __restrict__ er, const float* __restrict__ esh,
    const int* __restrict__ esrc, const int* __restrict__ edst,
    const float* __restrict__ h, const float* __restrict__ Wfc,
    float* __restrict__ acc){
  int e = blockIdx.x*256 + threadIdx.x;
  if (e >= kEdges) return;
  float4 ra = *(const float4*)(er + e*8);
  float4 rb = *(const float4*)(er + e*8 + 4);
  float r[8] = {ra.x,ra.y,ra.z,ra.w,rb.x,rb.y,rb.z,rb.w};
  float4 sh4 = *(const float4*)(esh + e*4);
  const float s0 = sh4.x, s1 = sh4.y, s2 = sh4.z, s3 = sh4.w;
  const int src = esrc[e], dst = edst[e];
  const float* hp = h + src*kDim;

  float t00[16], t11[16], t01[8], t10x[8], t10y[8], t10z[8];
  #pragma unroll
  for (int w=0; w<16; ++w){ t00[w]=0.f; t11[w]=0.f; }
  #pragma unroll
  for (int w=0; w<8; ++w){ t01[w]=0.f; t10x[w]=0.f; t10y[w]=0.f; t10z[w]=0.f; }

  // ---- blocks 00 & 01 (share hs[u]) ----
  #pragma unroll 1
  for (int u=0; u<16; ++u){
    const float xu = hp[u];
    const float* w0 = Wfc + u*16;            // w00 row (u*16 + w)
    #pragma unroll
    for (int w=0; w<16; ++w){
      float wv = r[0]*w0[w];
      #pragma unroll
      for (int b=1;b<8;++b) wv += r[b]*w0[b*kNW + w];
      t00[w] += xu*wv;
    }
    const float* w1 = Wfc + 256 + u*8;       // w01 row
    #pragma unroll
    for (int w=0; w<8; ++w){
      float wv = r[0]*w1[w];
      #pragma unroll
      for (int b=1;b<8;++b) wv += r[b]*w1[b*kNW + w];
      t01[w] += xu*wv;
    }
  }
  // ---- blocks 10 & 11 (share hv[u]) ----
  #pragma unroll 1
  for (int u=0; u<8; ++u){
    const float v0 = hp[16+u*3+0], v1 = hp[16+u*3+1], v2 = hp[16+u*3+2];
    const float au = v0*s1 + v1*s2 + v2*s3;  // xv[u]·sh1
    const float* w2 = Wfc + 384 + u*8;       // w10 row
    #pragma unroll
    for (int w=0; w<8; ++w){
      float wv = r[0]*w2[w];
      #pragma unroll
      for (int b=1;b<8;++b) wv += r[b]*w2[b*kNW + w];
      t10x[w] += v0*wv; t10y[w] += v1*wv; t10z[w] += v2*wv;
    }
    const float* w3 = Wfc + 448 + u*16;      // w11 row
    #pragma unroll
    for (int w=0; w<16; ++w){
      float wv = r[0]*w3[w];
      #pragma unroll
      for (int b=1;b<8;++b) wv += r[b]*w3[b*kNW + w];
      t11[w] += au*wv;
    }
  }

  // scales: inv2 * (1/sqrt8 from w-norm) * per-path norm
  constexpr float cs00 = 0.0625f;               // inv2/(sqrt8*4)
  constexpr float cs11 = 0.05103103630798288f;  // inv2/(sqrt8*sqrt24) = 1/sqrt(384)
  constexpr float cv01 = 0.0625f;
  constexpr float cv10 = 0.08838834764831845f;  // inv2/8

  float* ap = acc + dst*kDim;
  #pragma unroll
  for (int w=0; w<16; ++w)
    atomicAdd(&ap[w], s0*t00[w]*cs00 + t11[w]*cs11);
  #pragma unroll
  for (int w=0; w<8; ++w){
    atomicAdd(&ap[16+w*3+0], s1*t01[w]*cv01 + s0*t10x[w]*cv10);
    atomicAdd(&ap[16+w*3+1], s2*t01[w]*cv01 + s0*t10y[w]*cv10);
    atomicAdd(&ap[16+w*3+2], s3*t01[w]*cv01 + s0*t10z[w]*cv10);
  }
}

// ---------------- finalize: scalar outputs (w = 0..15) ----------------
__global__ void __launch_bounds__(256) k_fin_s(
    const float* __restrict__ x, const float* __restrict__ acc,
    const float* __restrict__ W2s, const float* __restrict__ R00,
    const float* __restrict__ R11, float* __restrict__ out){
  int t = blockIdx.x*256 + threadIdx.x;
  if (t >= kNodes*16) return;
  int n = t >> 4, w = t & 15;
  const float* ap = acc + n*kDim;
  float hsum = 0.f;
  #pragma unroll
  for (int u=0;u<16;++u) hsum += ap[u]*W2s[u*16+w];
  hsum *= 0.0625f;                       // (1/deg=1/4) * (1/sqrt16=1/4)
  float ns = sqrtf(hsum*hsum + 1e-16f);
  float val = hsum/ns*sspf(ns);
  const float* xp = x + n*kDim;
  float r0 = 0.f;
  #pragma unroll 1
  for (int u=0;u<16;++u){
    float tacc = 0.f;
    #pragma unroll
    for (int v=0;v<16;++v) tacc += xp[v]*R00[(u*16+v)*16+w];
    r0 += xp[u]*tacc;
  }
  float r1 = 0.f;
  #pragma unroll 1
  for (int u=0;u<8;++u){
    float u0=xp[16+u*3], u1=xp[16+u*3+1], u2=xp[16+u*3+2];
    float tacc=0.f;
    #pragma unroll
    for (int v=0;v<8;++v){
      float dot = u0*xp[16+v*3] + u1*xp[16+v*3+1] + u2*xp[16+v*3+2];
      tacc += dot*R11[(u*8+v)*16+w];
    }
    r1 += tacc;
  }
  // inv2/16 = 0.044194..., inv2/sqrt(192) = 1/sqrt(384)
  out[n*kDim + w] = val + 0.04419417382415922f*r0 + 0.05103103630798288f*r1;
}

// ---------------- finalize: vector outputs (w = 0..7, i = 0..2) ----------------
__global__ void __launch_bounds__(256) k_fin_v(
    const float* __restrict__ x, const float* __restrict__ acc,
    const float* __restrict__ W2v, const float* __restrict__ R01,
    const float* __restrict__ R10, float* __restrict__ out){
  int t = blockIdx.x*256 + threadIdx.x;
  if (t >= kNodes*24) return;
  int n = t/24; int c = t - n*24; int w = c/3; int i = c - w*3;
  const float* ap = acc + n*kDim + 16;
  float h0=0.f,h1=0.f,h2=0.f;
  #pragma unroll
  for (int u=0;u<8;++u){
    float wv = W2v[u*8+w];
    h0 += ap[u*3+0]*wv; h1 += ap[u*3+1]*wv; h2 += ap[u*3+2]*wv;
  }
  const float sc = 0.08838834764831845f;   // (1/4) * (1/sqrt8)
  h0*=sc; h1*=sc; h2*=sc;
  float nv = sqrtf(h0*h0+h1*h1+h2*h2 + 1e-16f);
  float hi = (i==0)?h0:((i==1)?h1:h2);
  float val = hi/nv*sspf(nv);
  const float* xp = x + n*kDim;
  float racc = 0.f;
  #pragma unroll 1
  for (int u=0;u<16;++u){           // R01: sum_u xs[u] * sum_v xv[v,i] R01[u,v,w]
    float tacc=0.f;
    #pragma unroll
    for (int v=0;v<8;++v) tacc += xp[16+v*3+i]*R01[(u*8+v)*8+w];
    racc += xp[u]*tacc;
  }
  #pragma unroll 1
  for (int u=0;u<8;++u){            // R10: sum_u xv[u,i] * sum_v xs[v] R10[u,v,w]
    float tacc=0.f;
    #pragma unroll
    for (int v=0;v<16;++v) tacc += xp[v]*R10[(u*16+v)*8+w];
    racc += xp[16+u*3+i]*tacc;
  }
  // inv2/sqrt(128) = 0.0625
  out[n*kDim + 16 + w*3 + i] = val + 0.0625f*racc;
}

extern "C" void kernel_launch(void* const* d_in, const int* in_sizes, int n_in,
                              void* d_out, int out_size, void* d_ws, size_t ws_size,
                              hipStream_t stream){
  const float* x   = (const float*)d_in[0];
  const float* er  = (const float*)d_in[1];
  const float* esh = (const float*)d_in[2];
  const int*   esrc= (const int*)d_in[3];
  const int*   edst= (const int*)d_in[4];
  // d_in[5] = n_nodes scalar (fixed 10000)
  const float* W1s = (const float*)d_in[6];
  const float* W1v = (const float*)d_in[7];
  const float* Wfc = (const float*)d_in[8];
  const float* W2s = (const float*)d_in[9];
  const float* W2v = (const float*)d_in[10];
  const float* R00 = (const float*)d_in[11];
  const float* R01 = (const float*)d_in[12];
  const float* R10 = (const float*)d_in[13];
  const float* R11 = (const float*)d_in[14];
  float* out = (float*)d_out;
  float* h   = (float*)d_ws;                 // kNodes*kDim floats
  float* acc = h + kNodes*kDim;              // kNodes*kDim floats (accumulator)

  hipMemsetAsync(acc, 0, kNodes*kDim*sizeof(float), stream);
  k_prep<<<(kNodes+255)/256, 256, 0, stream>>>(x, W1s, W1v, h);
  k_edge<<<(kEdges+255)/256, 256, 0, stream>>>(er, esh, esrc, edst, h, Wfc, acc);
  k_fin_s<<<(kNodes*16+255)/256, 256, 0, stream>>>(x, acc, W2s, R00, R11, out);
  k_fin_v<<<(kNodes*24+255)/256, 256, 0, stream>>>(x, acc, W2v, R01, R10, out);
}

// Round 2
// 217.121 us; speedup vs baseline: 2.3234x; 2.3234x over previous
//
#include <hip/hip_runtime.h>
#include <math.h>

constexpr int kM0 = 16, kM1 = 8, kDim = 40, kNW = 576;
constexpr int kNodes = 10000, kEdges = 160000;

__device__ __forceinline__ float sspf(float x){
  // softplus(x) - ln2  (numerically stable)
  float ax = fabsf(x);
  return fmaxf(x, 0.f) + log1pf(expf(-ax)) - 0.69314718055994531f;
}

// ---------------- h = _lin(x, W1s, W1v) ----------------
__global__ void __launch_bounds__(256) k_prep(
    const float* __restrict__ x, const float* __restrict__ W1s,
    const float* __restrict__ W1v, float* __restrict__ h){
  int n = blockIdx.x*256 + threadIdx.x;
  if (n >= kNodes) return;
  const float* xp = x + n*kDim;
  float* hp = h + n*kDim;
  #pragma unroll
  for (int v=0; v<kM0; ++v){
    float acc = 0.f;
    #pragma unroll
    for (int u=0; u<kM0; ++u) acc += xp[u]*W1s[u*kM0+v];
    hp[v] = acc*0.25f;                       // 1/sqrt(16)
  }
  #pragma unroll
  for (int v=0; v<kM1; ++v){
    float a0=0.f,a1=0.f,a2=0.f;
    #pragma unroll
    for (int u=0; u<kM1; ++u){
      float wv = W1v[u*kM1+v];
      a0 += xp[16+u*3+0]*wv;
      a1 += xp[16+u*3+1]*wv;
      a2 += xp[16+u*3+2]*wv;
    }
    hp[16+v*3+0]=a0*0.35355339059327373f;    // 1/sqrt(8)
    hp[16+v*3+1]=a1*0.35355339059327373f;
    hp[16+v*3+2]=a2*0.35355339059327373f;
  }
}

// ---------------- CSR build: histogram / scan / fill ----------------
__global__ void __launch_bounds__(256) k_hist(
    const int* __restrict__ edst, int* __restrict__ cnt){
  int e = blockIdx.x*256 + threadIdx.x;
  if (e < kEdges) atomicAdd(&cnt[edst[e]], 1);
}

__global__ void __launch_bounds__(1024) k_scan(
    const int* __restrict__ cnt, int* __restrict__ offs, int* __restrict__ cursor){
  __shared__ int part[1024];
  int t = threadIdx.x;
  int base = t*10;                 // 1024*10 >= 10000
  int local[10];
  int s = 0;
  #pragma unroll
  for (int k=0;k<10;++k){
    int idx = base+k;
    int c = (idx<kNodes) ? cnt[idx] : 0;
    local[k] = s; s += c;
  }
  part[t] = s; __syncthreads();
  for (int d=1; d<1024; d<<=1){
    int v = part[t];
    int add = (t>=d) ? part[t-d] : 0;
    __syncthreads();
    part[t] = v + add;
    __syncthreads();
  }
  int excl = (t>0) ? part[t-1] : 0;
  #pragma unroll
  for (int k=0;k<10;++k){
    int idx = base+k;
    if (idx<kNodes){ int o = excl + local[k]; offs[idx]=o; cursor[idx]=o; }
  }
  if (t==1023) offs[kNodes] = part[1023];
}

__global__ void __launch_bounds__(256) k_fill(
    const int* __restrict__ edst, int* __restrict__ cursor, int* __restrict__ elist){
  int e = blockIdx.x*256 + threadIdx.x;
  if (e < kEdges){
    int p = atomicAdd(&cursor[edst[e]], 1);
    elist[p] = e;
  }
}

// ---------------- per-edge messages (no atomics: store to msg[e]) ----------------
__global__ void __launch_bounds__(256) k_edge(
    const float* __restrict__ er, const float* __restrict__ esh,
    const int* __restrict__ esrc,
    const float* __restrict__ h, const float* __restrict__ Wfc,
    float* __restrict__ msg){
  int e = blockIdx.x*256 + threadIdx.x;
  if (e >= kEdges) return;
  float4 ra = *(const float4*)(er + e*8);
  float4 rb = *(const float4*)(er + e*8 + 4);
  float r[8] = {ra.x,ra.y,ra.z,ra.w,rb.x,rb.y,rb.z,rb.w};
  float4 sh4 = *(const float4*)(esh + e*4);
  const float s0 = sh4.x, s1 = sh4.y, s2 = sh4.z, s3 = sh4.w;
  const int src = esrc[e];
  const float* hp = h + src*kDim;

  float t00[16], t11[16], t01[8], t10x[8], t10y[8], t10z[8];
  #pragma unroll
  for (int w=0; w<16; ++w){ t00[w]=0.f; t11[w]=0.f; }
  #pragma unroll
  for (int w=0; w<8; ++w){ t01[w]=0.f; t10x[w]=0.f; t10y[w]=0.f; t10z[w]=0.f; }

  // ---- blocks 00 & 01 (share hs[u]) ----
  #pragma unroll 1
  for (int u=0; u<16; ++u){
    const float xu = hp[u];
    const float* w0 = Wfc + u*16;            // w00 row (u*16 + w)
    #pragma unroll
    for (int w=0; w<16; ++w){
      float wv = r[0]*w0[w];
      #pragma unroll
      for (int b=1;b<8;++b) wv += r[b]*w0[b*kNW + w];
      t00[w] += xu*wv;
    }
    const float* w1 = Wfc + 256 + u*8;       // w01 row
    #pragma unroll
    for (int w=0; w<8; ++w){
      float wv = r[0]*w1[w];
      #pragma unroll
      for (int b=1;b<8;++b) wv += r[b]*w1[b*kNW + w];
      t01[w] += xu*wv;
    }
  }
  // ---- blocks 10 & 11 (share hv[u]) ----
  #pragma unroll 1
  for (int u=0; u<8; ++u){
    const float v0 = hp[16+u*3+0], v1 = hp[16+u*3+1], v2 = hp[16+u*3+2];
    const float au = v0*s1 + v1*s2 + v2*s3;  // xv[u]·sh1
    const float* w2 = Wfc + 384 + u*8;       // w10 row
    #pragma unroll
    for (int w=0; w<8; ++w){
      float wv = r[0]*w2[w];
      #pragma unroll
      for (int b=1;b<8;++b) wv += r[b]*w2[b*kNW + w];
      t10x[w] += v0*wv; t10y[w] += v1*wv; t10z[w] += v2*wv;
    }
    const float* w3 = Wfc + 448 + u*16;      // w11 row
    #pragma unroll
    for (int w=0; w<16; ++w){
      float wv = r[0]*w3[w];
      #pragma unroll
      for (int b=1;b<8;++b) wv += r[b]*w3[b*kNW + w];
      t11[w] += au*wv;
    }
  }

  // scales: inv2 * (1/sqrt8 from w-norm) * per-path norm
  constexpr float cs00 = 0.0625f;               // inv2/(sqrt8*4)
  constexpr float cs11 = 0.05103103630798288f;  // inv2/(sqrt8*sqrt24) = 1/sqrt(384)
  constexpr float cv01 = 0.0625f;
  constexpr float cv10 = 0.08838834764831845f;  // inv2/8

  float m[40];
  #pragma unroll
  for (int w=0; w<16; ++w) m[w] = s0*t00[w]*cs00 + t11[w]*cs11;
  #pragma unroll
  for (int w=0; w<8; ++w){
    m[16+w*3+0] = s1*t01[w]*cv01 + s0*t10x[w]*cv10;
    m[16+w*3+1] = s2*t01[w]*cv01 + s0*t10y[w]*cv10;
    m[16+w*3+2] = s3*t01[w]*cv01 + s0*t10z[w]*cv10;
  }
  float* mp = msg + (size_t)e*kDim;
  #pragma unroll
  for (int o=0;o<40;o+=4)
    *(float4*)(mp+o) = make_float4(m[o],m[o+1],m[o+2],m[o+3]);
}

// ---------------- gather: one wave per node, lane j<40 owns component j ----------------
__global__ void __launch_bounds__(256) k_gather(
    const float* __restrict__ msg, const int* __restrict__ offs,
    const int* __restrict__ elist, float* __restrict__ acc){
  int wave = (blockIdx.x*256 + threadIdx.x) >> 6;
  int lane = threadIdx.x & 63;
  if (wave >= kNodes) return;
  int beg = offs[wave], end = offs[wave+1];
  if (lane < kDim){
    float a = 0.f;
    for (int k=beg; k<end; ++k){
      int e = elist[k];                      // wave-uniform (broadcast)
      a += msg[(size_t)e*kDim + lane];
    }
    acc[wave*kDim + lane] = a;
  }
}

// ---------------- finalize: scalar outputs (w = 0..15) ----------------
__global__ void __launch_bounds__(256) k_fin_s(
    const float* __restrict__ x, const float* __restrict__ acc,
    const float* __restrict__ W2s, const float* __restrict__ R00,
    const float* __restrict__ R11, float* __restrict__ out){
  int t = blockIdx.x*256 + threadIdx.x;
  if (t >= kNodes*16) return;
  int n = t >> 4, w = t & 15;
  const float* ap = acc + n*kDim;
  float hsum = 0.f;
  #pragma unroll
  for (int u=0;u<16;++u) hsum += ap[u]*W2s[u*16+w];
  hsum *= 0.0625f;                       // (1/deg=1/4) * (1/sqrt16=1/4)
  float ns = sqrtf(hsum*hsum + 1e-16f);
  float val = hsum/ns*sspf(ns);
  const float* xp = x + n*kDim;
  float r0 = 0.f;
  #pragma unroll 1
  for (int u=0;u<16;++u){
    float tacc = 0.f;
    #pragma unroll
    for (int v=0;v<16;++v) tacc += xp[v]*R00[(u*16+v)*16+w];
    r0 += xp[u]*tacc;
  }
  float r1 = 0.f;
  #pragma unroll 1
  for (int u=0;u<8;++u){
    float u0=xp[16+u*3], u1=xp[16+u*3+1], u2=xp[16+u*3+2];
    float tacc=0.f;
    #pragma unroll
    for (int v=0;v<8;++v){
      float dot = u0*xp[16+v*3] + u1*xp[16+v*3+1] + u2*xp[16+v*3+2];
      tacc += dot*R11[(u*8+v)*16+w];
    }
    r1 += tacc;
  }
  // inv2/16 = 0.044194..., inv2/sqrt(192) = 1/sqrt(384)
  out[n*kDim + w] = val + 0.04419417382415922f*r0 + 0.05103103630798288f*r1;
}

// ---------------- finalize: vector outputs (w = 0..7, i = 0..2) ----------------
__global__ void __launch_bounds__(256) k_fin_v(
    const float* __restrict__ x, const float* __restrict__ acc,
    const float* __restrict__ W2v, const float* __restrict__ R01,
    const float* __restrict__ R10, float* __restrict__ out){
  int t = blockIdx.x*256 + threadIdx.x;
  if (t >= kNodes*24) return;
  int n = t/24; int c = t - n*24; int w = c/3; int i = c - w*3;
  const float* ap = acc + n*kDim + 16;
  float h0=0.f,h1=0.f,h2=0.f;
  #pragma unroll
  for (int u=0;u<8;++u){
    float wv = W2v[u*8+w];
    h0 += ap[u*3+0]*wv; h1 += ap[u*3+1]*wv; h2 += ap[u*3+2]*wv;
  }
  const float sc = 0.08838834764831845f;   // (1/4) * (1/sqrt8)
  h0*=sc; h1*=sc; h2*=sc;
  float nv = sqrtf(h0*h0+h1*h1+h2*h2 + 1e-16f);
  float hi = (i==0)?h0:((i==1)?h1:h2);
  float val = hi/nv*sspf(nv);
  const float* xp = x + n*kDim;
  float racc = 0.f;
  #pragma unroll 1
  for (int u=0;u<16;++u){           // R01: sum_u xs[u] * sum_v xv[v,i] R01[u,v,w]
    float tacc=0.f;
    #pragma unroll
    for (int v=0;v<8;++v) tacc += xp[16+v*3+i]*R01[(u*8+v)*8+w];
    racc += xp[u]*tacc;
  }
  #pragma unroll 1
  for (int u=0;u<8;++u){            // R10: sum_u xv[u,i] * sum_v xs[v] R10[u,v,w]
    float tacc=0.f;
    #pragma unroll
    for (int v=0;v<16;++v) tacc += xp[v]*R10[(u*16+v)*8+w];
    racc += xp[16+u*3+i]*tacc;
  }
  // inv2/sqrt(128) = 0.0625
  out[n*kDim + 16 + w*3 + i] = val + 0.0625f*racc;
}

extern "C" void kernel_launch(void* const* d_in, const int* in_sizes, int n_in,
                              void* d_out, int out_size, void* d_ws, size_t ws_size,
                              hipStream_t stream){
  const float* x   = (const float*)d_in[0];
  const float* er  = (const float*)d_in[1];
  const float* esh = (const float*)d_in[2];
  const int*   esrc= (const int*)d_in[3];
  const int*   edst= (const int*)d_in[4];
  // d_in[5] = n_nodes scalar (fixed 10000)
  const float* W1s = (const float*)d_in[6];
  const float* W1v = (const float*)d_in[7];
  const float* Wfc = (const float*)d_in[8];
  const float* W2s = (const float*)d_in[9];
  const float* W2v = (const float*)d_in[10];
  const float* R00 = (const float*)d_in[11];
  const float* R01 = (const float*)d_in[12];
  const float* R10 = (const float*)d_in[13];
  const float* R11 = (const float*)d_in[14];
  float* out = (float*)d_out;

  // ws layout (all 4-byte types; float4 stores need 16B alignment — all offsets
  // below are multiples of 16B from the base)
  char* wsb = (char*)d_ws;
  float* h      = (float*)wsb;                                   // 400000 f
  float* acc    = h + (size_t)kNodes*kDim;                       // 400000 f
  float* msg    = acc + (size_t)kNodes*kDim;                     // 6.4M f
  int*   cnt    = (int*)(msg + (size_t)kEdges*kDim);             // 10000
  int*   offs   = cnt + kNodes;                                  // 10001
  int*   cursor = offs + kNodes + 1;                             // 10000
  int*   elist  = cursor + kNodes;                               // 160000

  hipMemsetAsync(cnt, 0, kNodes*sizeof(int), stream);
  k_prep<<<(kNodes+255)/256, 256, 0, stream>>>(x, W1s, W1v, h);
  k_hist<<<(kEdges+255)/256, 256, 0, stream>>>(edst, cnt);
  k_scan<<<1, 1024, 0, stream>>>(cnt, offs, cursor);
  k_fill<<<(kEdges+255)/256, 256, 0, stream>>>(edst, cursor, elist);
  k_edge<<<(kEdges+255)/256, 256, 0, stream>>>(er, esh, esrc, h, Wfc, msg);
  k_gather<<<(kNodes*64+255)/256, 256, 0, stream>>>(msg, offs, elist, acc);
  k_fin_s<<<(kNodes*16+255)/256, 256, 0, stream>>>(x, acc, W2s, R00, R11, out);
  k_fin_v<<<(kNodes*24+255)/256, 256, 0, stream>>>(x, acc, W2v, R01, R10, out);
}